// Round 2
// baseline (797.489 us; speedup 1.0000x reference)
//
#include <hip/hip_runtime.h>
#include <stdint.h>

#define B_  4
#define S_  4096
#define D_  1024
#define H_  16
#define R_  256
#define HD_ 64
#define BH_ 64        // B_*H_
#define M_  16384     // B_*S_
#define SPLITK_ 4     // kv split-K partials (kvp aliases x_lo: 4*64*256*80*4 = 21 MB <= 33.5 MB)

typedef uint16_t u16;
typedef __attribute__((ext_vector_type(8))) short short8;
typedef __attribute__((ext_vector_type(4))) float f32x4;
typedef __attribute__((ext_vector_type(4))) unsigned short us4;

__device__ __forceinline__ u16 f2bf(float f){
  union { float f; uint32_t u; } v; v.f = f;
  uint32_t r = v.u + 0x7FFFu + ((v.u >> 16) & 1u);
  return (u16)(r >> 16);
}
__device__ __forceinline__ float bf2f(u16 h){
  union { uint32_t u; float f; } v; v.u = ((uint32_t)h) << 16;
  return v.f;
}
__device__ __forceinline__ f32x4 mfma16(short8 a, short8 b, f32x4 c){
  return __builtin_amdgcn_mfma_f32_16x16x32_bf16(a, b, c, 0, 0, 0);
}
// split a float8 (two float4) into bf16 hi + lo fragments
__device__ __forceinline__ void cvt8(const float4& a, const float4& b, short8& hi, short8& lo){
  float f[8] = {a.x,a.y,a.z,a.w,b.x,b.y,b.z,b.w};
  #pragma unroll
  for (int j=0;j<8;j++){
    u16 h = f2bf(f[j]);
    hi[j] = (short)h;
    lo[j] = (short)f2bf(f[j] - bf2f(h));
  }
}

// ---------------- prep kernels ----------------
__global__ void split_kernel(const float* __restrict__ src, u16* __restrict__ hi,
                             u16* __restrict__ lo, int n4){
  int i = blockIdx.x*blockDim.x + threadIdx.x;
  if (i >= n4) return;
  float4 f = ((const float4*)src)[i];
  float ff[4] = {f.x,f.y,f.z,f.w};
  us4 hv, lv;
  #pragma unroll
  for (int j=0;j<4;j++){
    u16 h = f2bf(ff[j]);
    hv[j] = h;
    lv[j] = f2bf(ff[j] - bf2f(h));
  }
  ((us4*)hi)[i] = hv;
  if (lo) ((us4*)lo)[i] = lv;
}

// rf [H][HD][R] fp32 -> rf_t hi/lo [H][R][HD] bf16
__global__ void rf_split_kernel(const float* __restrict__ rf, u16* __restrict__ rhi,
                                u16* __restrict__ rlo){
  int idx = blockIdx.x*256 + threadIdx.x;     // over H*R*HD = 262144
  int d = idx & 63, r = (idx >> 6) & 255, h = idx >> 14;
  float f = rf[((size_t)h*HD_ + d)*R_ + r];
  u16 hh = f2bf(f);
  rhi[idx] = hh;
  rlo[idx] = f2bf(f - bf2f(hh));
}

// sq[row] = 0.5 * sum_d src[row][d]^2 ; row dim = HD_=64, one wave per row
__global__ void sqhalf_kernel(const float* __restrict__ src, float* __restrict__ sq){
  int row  = blockIdx.x*4 + (threadIdx.x >> 6);
  int lane = threadIdx.x & 63;
  float v = src[(size_t)row*HD_ + lane];
  float s = v*v;
  #pragma unroll
  for (int o=32; o>0; o >>= 1) s += __shfl_down(s, o);
  if (lane == 0) sq[row] = 0.5f*s;
}

// ---------------- 128x128 MFMA GEMM, K=1024, A[M][K], B[N][K] (both bf16) ----------------
// Staging: register prefetch + ds_write_b128 (no global_load_lds this round — crash isolation).
// LDS layout per tile buffer: row r (0..127) at r*32 u16; 16B-group position p holds global
// group g = p ^ ((r>>1)&3)   (XOR swizzle -> reads/writes are 2-way = free)
// NSPLIT==3: acc += Ah*Bh + Ah*Bl + Al*Bh   (split-bf16 ~fp32 precision)
// EPI 0: fp32 out to [b,h,s,hd]  (m=(b,s), n=(h,hd)) + bias
// EPI 1: bf16 out transposed to [b,h,hd,s] + bias
// EPI 2: fp32 out to [m][n] + bias
template<int NSPLIT, int EPI>
__global__ __launch_bounds__(256, 2)
void gemm128(const u16* __restrict__ Ah, const u16* __restrict__ Al,
             const u16* __restrict__ Bh, const u16* __restrict__ Bl,
             const float* __restrict__ bias, float* __restrict__ outF,
             u16* __restrict__ outB){
  constexpr int NBUF = (NSPLIT==3) ? 4 : 2;
  __shared__ u16 lds[NBUF * 4096];
  const int tid = threadIdx.x, w = tid >> 6, lane = tid & 63;
  const int wm = w & 1, wn = w >> 1;
  const int m0 = blockIdx.x * 128, n0 = blockIdx.y * 128;
  const int q = lane >> 4, rr = lane & 15;

  // staging geometry: thread t loads rows srow and srow+64, 16B group sgrp
  const int srow = tid >> 2, sgrp = tid & 3;
  const int l0 = srow*32      + (sgrp ^ ((srow >> 1) & 3))*8;
  const int l1 = (srow+64)*32 + (sgrp ^ (((srow+64) >> 1) & 3))*8;
  const size_t ga0 = (size_t)(m0 + srow)*1024      + sgrp*8;
  const size_t ga1 = (size_t)(m0 + srow + 64)*1024 + sgrp*8;
  const size_t gb0 = (size_t)(n0 + srow)*1024      + sgrp*8;
  const size_t gb1 = (size_t)(n0 + srow + 64)*1024 + sgrp*8;

  f32x4 acc[4][4];
  #pragma unroll
  for (int i=0;i<4;i++)
    #pragma unroll
    for (int j=0;j<4;j++) acc[i][j] = f32x4{0.f,0.f,0.f,0.f};

  short8 st[NSPLIT==3 ? 8 : 4];
  auto loadTile = [&](int kt){
    const int k0 = kt*32;
    st[0] = *(const short8*)(Ah + ga0 + k0);
    st[1] = *(const short8*)(Ah + ga1 + k0);
    st[2] = *(const short8*)(Bh + gb0 + k0);
    st[3] = *(const short8*)(Bh + gb1 + k0);
    if constexpr (NSPLIT == 3){
      st[4] = *(const short8*)(Al + ga0 + k0);
      st[5] = *(const short8*)(Al + ga1 + k0);
      st[6] = *(const short8*)(Bl + gb0 + k0);
      st[7] = *(const short8*)(Bl + gb1 + k0);
    }
  };
  auto storeTile = [&](){
    *(short8*)(lds + 0*4096 + l0) = st[0];
    *(short8*)(lds + 0*4096 + l1) = st[1];
    *(short8*)(lds + 1*4096 + l0) = st[2];
    *(short8*)(lds + 1*4096 + l1) = st[3];
    if constexpr (NSPLIT == 3){
      *(short8*)(lds + 2*4096 + l0) = st[4];
      *(short8*)(lds + 2*4096 + l1) = st[5];
      *(short8*)(lds + 3*4096 + l0) = st[6];
      *(short8*)(lds + 3*4096 + l1) = st[7];
    }
  };

  loadTile(0);
  for (int kt=0; kt<32; kt++){
    storeTile();
    __syncthreads();
    if (kt+1 < 32) loadTile(kt+1);   // prefetch overlaps MFMA below

    short8 afh[4], bfh[4], afl[4], bfl[4];
    #pragma unroll
    for (int i=0;i<4;i++){
      int r  = wm*64 + i*16 + rr;
      int o  = r*32 + ((q ^ ((r >> 1) & 3))*8);
      afh[i] = *(const short8*)(lds + 0*4096 + o);
      if constexpr (NSPLIT == 3) afl[i] = *(const short8*)(lds + 2*4096 + o);
      int rn = wn*64 + i*16 + rr;
      int on = rn*32 + ((q ^ ((rn >> 1) & 3))*8);
      bfh[i] = *(const short8*)(lds + 1*4096 + on);
      if constexpr (NSPLIT == 3) bfl[i] = *(const short8*)(lds + 3*4096 + on);
    }
    #pragma unroll
    for (int i=0;i<4;i++)
      #pragma unroll
      for (int j=0;j<4;j++){
        acc[i][j] = mfma16(afh[i], bfh[j], acc[i][j]);
        if constexpr (NSPLIT == 3){
          acc[i][j] = mfma16(afh[i], bfl[j], acc[i][j]);
          acc[i][j] = mfma16(afl[i], bfh[j], acc[i][j]);
        }
      }
    __syncthreads();
  }

  // epilogue
  #pragma unroll
  for (int i=0;i<4;i++){
    #pragma unroll
    for (int j=0;j<4;j++){
      int n  = n0 + wn*64 + j*16 + rr;
      float bb = bias[n];
      if constexpr (EPI == 1){
        int mb = m0 + wm*64 + i*16 + q*4;
        us4 pk;
        #pragma unroll
        for (int r4=0;r4<4;r4++) pk[r4] = f2bf(acc[i][j][r4] + bb);
        *(us4*)(outB + ((size_t)((mb >> 12)*H_ + (n >> 6))*HD_ + (n & 63))*S_ + (mb & 4095)) = pk;
      } else {
        #pragma unroll
        for (int r4=0;r4<4;r4++){
          int m = m0 + wm*64 + i*16 + q*4 + r4;
          float v = acc[i][j][r4] + bb;
          if constexpr (EPI == 0)
            outF[((size_t)((m >> 12)*H_ + (n >> 6)))*S_*HD_ + (size_t)(m & 4095)*HD_ + (n & 63)] = v;
          else
            outF[(size_t)m*1024 + n] = v;
        }
      }
    }
  }
}

// ---------------- fused k-feature + kv' split-K partial ----------------
// grid (BH_, SPLITK_); block covers S_/SPLITK_ s per (b,h); sub-chunks of 64 s.
// phase1: k' = exp(k@RF - sq) -> LDS [r][s] (stride 72); phase2: kv += k'^T @ [v | 1]
__global__ __launch_bounds__(256, 1)
void kfeat_kv_kernel(const float* __restrict__ k32, const float* __restrict__ sqk,
                     const u16* __restrict__ rfh, const u16* __restrict__ rfl,
                     const u16* __restrict__ vt, float* __restrict__ kvp){
  __shared__ u16 kp[R_*72];
  const int hb = blockIdx.x, sp = blockIdx.y, h = hb & 15;
  const int tid = threadIdx.x, w = tid >> 6, lane = tid & 63;
  const int q = lane >> 4, rr = lane & 15;

  short8 ones;
  { u16 one = (rr == 0) ? (u16)0x3F80 : (u16)0;
    #pragma unroll
    for (int j=0;j<8;j++) ones[j] = (short)one; }

  f32x4 acc2[4][5];
  #pragma unroll
  for (int a=0;a<4;a++)
    #pragma unroll
    for (int t=0;t<5;t++) acc2[a][t] = f32x4{0.f,0.f,0.f,0.f};

  for (int sub=0; sub<(S_/SPLITK_)/64; sub++){
    const int s0 = sp*(S_/SPLITK_) + sub*64;
    // ---- phase 1: feature map for 64 s rows (wave w owns rows w*16..w*16+15) ----
    const float* ap = k32 + ((size_t)hb*S_ + s0 + w*16 + rr)*HD_ + q*8;
    float4 x0 = *(const float4*)(ap);
    float4 x1 = *(const float4*)(ap + 4);
    float4 x2 = *(const float4*)(ap + 32);
    float4 x3 = *(const float4*)(ap + 36);
    short8 ah[2], al[2];
    cvt8(x0, x1, ah[0], al[0]);
    cvt8(x2, x3, ah[1], al[1]);
    float sql[4];
    #pragma unroll
    for (int r4=0;r4<4;r4++) sql[r4] = sqk[(size_t)hb*S_ + s0 + w*16 + q*4 + r4];

    f32x4 accp[16];
    #pragma unroll
    for (int t=0;t<16;t++) accp[t] = f32x4{0.f,0.f,0.f,0.f};
    #pragma unroll
    for (int t=0;t<16;t++){
      const u16* bp  = rfh + ((size_t)h*R_ + t*16 + rr)*HD_ + q*8;
      const u16* bpl = rfl + ((size_t)h*R_ + t*16 + rr)*HD_ + q*8;
      short8 bh0 = *(const short8*)(bp);
      short8 bh1 = *(const short8*)(bp + 32);
      short8 bl0 = *(const short8*)(bpl);
      short8 bl1 = *(const short8*)(bpl + 32);
      f32x4 c = accp[t];
      c = mfma16(ah[0], bh0, c); c = mfma16(ah[0], bl0, c); c = mfma16(al[0], bh0, c);
      c = mfma16(ah[1], bh1, c); c = mfma16(ah[1], bl1, c); c = mfma16(al[1], bh1, c);
      accp[t] = c;
    }
    #pragma unroll
    for (int t=0;t<16;t++){
      us4 pk;
      #pragma unroll
      for (int r4=0;r4<4;r4++) pk[r4] = f2bf(__expf(accp[t][r4] - sql[r4]));
      *(us4*)(kp + (t*16 + rr)*72 + w*16 + q*4) = pk;
    }
    __syncthreads();
    // ---- phase 2: kv' += k'^T @ [v | 1] ; wave w owns r rows w*64..w*64+63 ----
    #pragma unroll
    for (int ks=0; ks<2; ks++){
      short8 af[4];
      #pragma unroll
      for (int a=0;a<4;a++)
        af[a] = *(const short8*)(kp + (w*64 + a*16 + rr)*72 + ks*32 + q*8);
      #pragma unroll
      for (int t=0;t<5;t++){
        short8 bf;
        if (t < 4)
          bf = *(const short8*)(vt + ((size_t)hb*HD_ + t*16 + rr)*S_ + s0 + ks*32 + q*8);
        else
          bf = ones;
        #pragma unroll
        for (int a=0;a<4;a++) acc2[a][t] = mfma16(af[a], bf, acc2[a][t]);
      }
    }
    __syncthreads();
  }
  float* op = kvp + ((size_t)hb*SPLITK_ + sp)*R_*80;
  #pragma unroll
  for (int a=0;a<4;a++)
    #pragma unroll
    for (int t=0;t<5;t++)
      #pragma unroll
      for (int r4=0;r4<4;r4++){
        int r = w*64 + a*16 + q*4 + r4;
        int c = t*16 + rr;
        op[r*80 + c] = acc2[a][t][r4];
      }
}

// reduce kv partials: kv_t[hb][d][r] bf16, ksum[hb][r] fp32
__global__ void kv_reduce_kernel(const float* __restrict__ kvp, u16* __restrict__ kvt,
                                 float* __restrict__ ksum){
  int r = blockIdx.x, hb = blockIdx.y, c = threadIdx.x;
  if (c >= 65) return;
  const float* base = kvp + (size_t)hb*SPLITK_*R_*80 + r*80 + c;
  float s = 0.f;
  #pragma unroll
  for (int sp=0; sp<SPLITK_; sp++) s += base[(size_t)sp*R_*80];
  if (c < 64) kvt[((size_t)hb*HD_ + c)*R_ + r] = f2bf(s);
  else        ksum[(size_t)hb*R_ + r] = s;
}

// ---------------- fused q-feature + attn + norm ----------------
// grid (BH_, 64); block = 64 s rows
__global__ __launch_bounds__(256, 1)
void qfeat_attn_kernel(const float* __restrict__ q32, const float* __restrict__ sqq,
                       const u16* __restrict__ rfh, const u16* __restrict__ rfl,
                       const u16* __restrict__ kvt, const float* __restrict__ ksum,
                       u16* __restrict__ attn_c){
  __shared__ u16 qp[64*264];
  __shared__ float ksl[R_];
  __shared__ float npart[256];
  __shared__ float normv[64];
  const int hb = blockIdx.x, sc = blockIdx.y, h = hb & 15, b = hb >> 4;
  const int tid = threadIdx.x, w = tid >> 6, lane = tid & 63;
  const int q = lane >> 4, rr = lane & 15;
  const int s0 = sc*64;

  ksl[tid] = ksum[(size_t)hb*R_ + tid];

  // ---- phase 1: q' for 64 s rows ----
  const float* ap = q32 + ((size_t)hb*S_ + s0 + w*16 + rr)*HD_ + q*8;
  float4 x0 = *(const float4*)(ap);
  float4 x1 = *(const float4*)(ap + 4);
  float4 x2 = *(const float4*)(ap + 32);
  float4 x3 = *(const float4*)(ap + 36);
  short8 ah[2], al[2];
  cvt8(x0, x1, ah[0], al[0]);
  cvt8(x2, x3, ah[1], al[1]);
  float sql[4];
  #pragma unroll
  for (int r4=0;r4<4;r4++) sql[r4] = sqq[(size_t)hb*S_ + s0 + w*16 + q*4 + r4];

  f32x4 accp[16];
  #pragma unroll
  for (int t=0;t<16;t++) accp[t] = f32x4{0.f,0.f,0.f,0.f};
  #pragma unroll
  for (int t=0;t<16;t++){
    const u16* bp  = rfh + ((size_t)h*R_ + t*16 + rr)*HD_ + q*8;
    const u16* bpl = rfl + ((size_t)h*R_ + t*16 + rr)*HD_ + q*8;
    short8 bh0 = *(const short8*)(bp);
    short8 bh1 = *(const short8*)(bp + 32);
    short8 bl0 = *(const short8*)(bpl);
    short8 bl1 = *(const short8*)(bpl + 32);
    f32x4 c = accp[t];
    c = mfma16(ah[0], bh0, c); c = mfma16(ah[0], bl0, c); c = mfma16(al[0], bh0, c);
    c = mfma16(ah[1], bh1, c); c = mfma16(ah[1], bl1, c); c = mfma16(al[1], bh1, c);
    accp[t] = c;
  }
  #pragma unroll
  for (int t=0;t<16;t++)
    #pragma unroll
    for (int r4=0;r4<4;r4++)
      qp[(w*16 + q*4 + r4)*264 + t*16 + rr] = f2bf(__expf(accp[t][r4] - sql[r4]));
  __syncthreads();

  // ---- norm partials: thread (row = tid&63, quarter p = tid>>6) ----
  {
    int row = tid & 63, pp = tid >> 6;
    const u16* qrow = qp + row*264 + pp*64;
    float np = 0.f;
    #pragma unroll 8
    for (int jj=0; jj<64; jj++) np += bf2f(qrow[jj]) * ksl[pp*64 + jj];
    npart[tid] = np;
  }

  // ---- phase 2: attn = q' @ kv'^T ; wave w owns s rows w*16..w*16+15 ----
  f32x4 acc[4];
  #pragma unroll
  for (int t=0;t<4;t++) acc[t] = f32x4{0.f,0.f,0.f,0.f};
  #pragma unroll
  for (int ks=0; ks<8; ks++){
    short8 af = *(const short8*)(qp + (w*16 + rr)*264 + ks*32 + q*8);
    #pragma unroll
    for (int t=0;t<4;t++){
      short8 bf = *(const short8*)(kvt + ((size_t)hb*HD_ + t*16 + rr)*R_ + ks*32 + q*8);
      acc[t] = mfma16(af, bf, acc[t]);
    }
  }
  __syncthreads();
  if (tid < 64)
    normv[tid] = (npart[tid] + npart[tid+64]) + (npart[tid+128] + npart[tid+192]);
  __syncthreads();

  #pragma unroll
  for (int t=0;t<4;t++)
    #pragma unroll
    for (int r4=0;r4<4;r4++){
      int sl = w*16 + q*4 + r4;
      int d  = t*16 + rr;
      float o = acc[t][r4] / (normv[sl] + 1e-6f);
      attn_c[((size_t)b*S_ + s0 + sl)*D_ + h*HD_ + d] = f2bf(o);
    }
}

// ---------------- host ----------------
extern "C" void kernel_launch(void* const* d_in, const int* in_sizes, int n_in,
                              void* d_out, int out_size, void* d_ws, size_t ws_size,
                              hipStream_t stream){
  (void)in_sizes; (void)n_in; (void)out_size; (void)ws_size;
  const float* x  = (const float*)d_in[0];
  const float* wq = (const float*)d_in[1];
  const float* bq = (const float*)d_in[2];
  const float* wk = (const float*)d_in[3];
  const float* bk = (const float*)d_in[4];
  const float* wv = (const float*)d_in[5];
  const float* bv = (const float*)d_in[6];
  const float* wo = (const float*)d_in[7];
  const float* bo = (const float*)d_in[8];
  const float* rf = (const float*)d_in[9];
  float* out = (float*)d_out;

  char* p = (char*)d_ws;
  size_t off = 0;
  auto take = [&](size_t bytes)->char*{
    char* r = p + off; off += (bytes + 255) & ~(size_t)255; return r;
  };
  u16*  x_hi  = (u16*)take((size_t)M_*D_*2);
  u16*  x_lo  = (u16*)take((size_t)M_*D_*2);
  u16*  wq_hi = (u16*)take((size_t)D_*D_*2);
  u16*  wq_lo = (u16*)take((size_t)D_*D_*2);
  u16*  wk_hi = (u16*)take((size_t)D_*D_*2);
  u16*  wk_lo = (u16*)take((size_t)D_*D_*2);
  u16*  wv_hi = (u16*)take((size_t)D_*D_*2);
  u16*  wo_hi = (u16*)take((size_t)D_*D_*2);
  u16*  rf_hi = (u16*)take((size_t)H_*R_*HD_*2);
  u16*  rf_lo = (u16*)take((size_t)H_*R_*HD_*2);
  float* q32  = (float*)take((size_t)M_*D_*4);
  float* k32  = (float*)take((size_t)M_*D_*4);
  float* sqq  = (float*)take((size_t)BH_*S_*4);
  float* sqk  = (float*)take((size_t)BH_*S_*4);
  u16*  v_t   = (u16*)take((size_t)M_*D_*2);
  u16*  kvt   = (u16*)take((size_t)BH_*HD_*R_*2);
  float* ksum = (float*)take((size_t)BH_*R_*4);
  // aliases (stream-ordered reuse of dead buffers):
  u16*   attn_c = x_hi;        // x_hi dead after V projection; attn_c written by qfeat
  float* kvp    = (float*)x_lo; // x_lo dead after K projection; kvp = 21 MB <= 33.5 MB

  // prep: splits
  split_kernel<<<dim3((M_*D_)/1024), 256, 0, stream>>>(x,  x_hi,  x_lo,  (M_*D_)/4);
  split_kernel<<<dim3((D_*D_)/1024), 256, 0, stream>>>(wq, wq_hi, wq_lo, (D_*D_)/4);
  split_kernel<<<dim3((D_*D_)/1024), 256, 0, stream>>>(wk, wk_hi, wk_lo, (D_*D_)/4);
  split_kernel<<<dim3((D_*D_)/1024), 256, 0, stream>>>(wv, wv_hi, nullptr, (D_*D_)/4);
  split_kernel<<<dim3((D_*D_)/1024), 256, 0, stream>>>(wo, wo_hi, nullptr, (D_*D_)/4);
  rf_split_kernel<<<dim3((H_*R_*HD_)/256), 256, 0, stream>>>(rf, rf_hi, rf_lo);

  // projections
  gemm128<3,0><<<dim3(M_/128, D_/128), 256, 0, stream>>>(x_hi, x_lo, wq_hi, wq_lo, bq, q32, nullptr);
  gemm128<3,0><<<dim3(M_/128, D_/128), 256, 0, stream>>>(x_hi, x_lo, wk_hi, wk_lo, bk, k32, nullptr);
  gemm128<1,1><<<dim3(M_/128, D_/128), 256, 0, stream>>>(x_hi, nullptr, wv_hi, nullptr, bv, nullptr, v_t);

  // row sq-norms
  sqhalf_kernel<<<dim3(BH_*S_/4), 256, 0, stream>>>(q32, sqq);
  sqhalf_kernel<<<dim3(BH_*S_/4), 256, 0, stream>>>(k32, sqk);

  // k' -> kv partials -> reduce
  kfeat_kv_kernel<<<dim3(BH_, SPLITK_), 256, 0, stream>>>(k32, sqk, rf_hi, rf_lo, v_t, kvp);
  kv_reduce_kernel<<<dim3(R_, BH_), 128, 0, stream>>>(kvp, kvt, ksum);

  // q' -> attn -> attn_c
  qfeat_attn_kernel<<<dim3(BH_, S_/64), 256, 0, stream>>>(q32, sqq, rf_hi, rf_lo, kvt, ksum, attn_c);

  // output projection
  gemm128<1,2><<<dim3(M_/128, D_/128), 256, 0, stream>>>(attn_c, nullptr, wo_hi, nullptr, bo, out, nullptr);
}

// Round 3
// 681.670 us; speedup vs baseline: 1.1699x; 1.1699x over previous
//
#include <hip/hip_runtime.h>
#include <stdint.h>

#define B_  4
#define S_  4096
#define D_  1024
#define H_  16
#define R_  256
#define HD_ 64
#define BH_ 64        // B_*H_
#define M_  16384     // B_*S_
#define SPLITK_ 8     // kv split-K partials, bf16: 8*64*256*80*2 = 21 MB <= x_lo (33.5 MB)

typedef uint16_t u16;
typedef __attribute__((ext_vector_type(8))) short short8;
typedef __attribute__((ext_vector_type(4))) float f32x4;
typedef __attribute__((ext_vector_type(4))) unsigned short us4;

__device__ __forceinline__ u16 f2bf(float f){
  union { float f; uint32_t u; } v; v.f = f;
  uint32_t r = v.u + 0x7FFFu + ((v.u >> 16) & 1u);
  return (u16)(r >> 16);
}
__device__ __forceinline__ float bf2f(u16 h){
  union { uint32_t u; float f; } v; v.u = ((uint32_t)h) << 16;
  return v.f;
}
__device__ __forceinline__ f32x4 mfma16(short8 a, short8 b, f32x4 c){
  return __builtin_amdgcn_mfma_f32_16x16x32_bf16(a, b, c, 0, 0, 0);
}
// async global->LDS DMA, 16B per lane; LDS dest = wave-uniform base + lane*16
__device__ __forceinline__ void gl_lds16(const u16* g, u16* l){
  __builtin_amdgcn_global_load_lds((const __attribute__((address_space(1))) void*)g,
                                   (__attribute__((address_space(3))) void*)l, 16, 0, 0);
}
// split a float8 (two float4) into bf16 hi + lo fragments
__device__ __forceinline__ void cvt8(const float4& a, const float4& b, short8& hi, short8& lo){
  float f[8] = {a.x,a.y,a.z,a.w,b.x,b.y,b.z,b.w};
  #pragma unroll
  for (int j=0;j<8;j++){
    u16 h = f2bf(f[j]);
    hi[j] = (short)h;
    lo[j] = (short)f2bf(f[j] - bf2f(h));
  }
}

// ---------------- prep kernels ----------------
__global__ void split_kernel(const float* __restrict__ src, u16* __restrict__ hi,
                             u16* __restrict__ lo, int n4){
  int i = blockIdx.x*blockDim.x + threadIdx.x;
  if (i >= n4) return;
  float4 f = ((const float4*)src)[i];
  float ff[4] = {f.x,f.y,f.z,f.w};
  us4 hv, lv;
  #pragma unroll
  for (int j=0;j<4;j++){
    u16 h = f2bf(ff[j]);
    hv[j] = h;
    lv[j] = f2bf(ff[j] - bf2f(h));
  }
  ((us4*)hi)[i] = hv;
  if (lo) ((us4*)lo)[i] = lv;
}

// rf [H][HD][R] fp32 -> rf_t hi/lo [H][R][HD] bf16
__global__ void rf_split_kernel(const float* __restrict__ rf, u16* __restrict__ rhi,
                                u16* __restrict__ rlo){
  int idx = blockIdx.x*256 + threadIdx.x;     // over H*R*HD = 262144
  int d = idx & 63, r = (idx >> 6) & 255, h = idx >> 14;
  float f = rf[((size_t)h*HD_ + d)*R_ + r];
  u16 hh = f2bf(f);
  rhi[idx] = hh;
  rlo[idx] = f2bf(f - bf2f(hh));
}

// fused ||row||^2/2: lane (q,rr) holds 16 elems of row w*16+rr.
// result sql[r4] = 0.5*||row w*16+q*4+r4||^2 on every lane (matches C-layout rows).
__device__ __forceinline__ void rowsq(const float4& x0, const float4& x1,
                                      const float4& x2, const float4& x3,
                                      int q, float sql[4]){
  float s = x0.x*x0.x + x0.y*x0.y + x0.z*x0.z + x0.w*x0.w
          + x1.x*x1.x + x1.y*x1.y + x1.z*x1.z + x1.w*x1.w
          + x2.x*x2.x + x2.y*x2.y + x2.z*x2.z + x2.w*x2.w
          + x3.x*x3.x + x3.y*x3.y + x3.z*x3.z + x3.w*x3.w;
  s += __shfl_xor(s, 16);
  s += __shfl_xor(s, 32);
  #pragma unroll
  for (int r4=0;r4<4;r4++) sql[r4] = 0.5f * __shfl(s, q*4 + r4);
}

// ---------------- 128x128 MFMA GEMM, K=1024, A[M][K], B[N][K] (both bf16) ----------------
// Staging: global_load_lds width=16 (m97 pattern, 2-barrier K-loop).
// LDS chunk layout (1 KB per 16 rows x 32 k): lane l -> row c*16+(l>>2), pos p=l&3;
// pos p holds global 16B-group g = p ^ ((row>>1)&3)  (XOR swizzle -> free 2-way reads)
// NSPLIT==3: acc += Ah*Bh + Ah*Bl + Al*Bh   (split-bf16 ~fp32 precision)
// EPI 0: fp32 -> [b,h,s,hd]+bias | EPI 1: bf16 -> [b,h,hd,s]+bias | EPI 2: fp32 [m][n]+bias
template<int NSPLIT, int EPI>
__global__ __launch_bounds__(256, 2)
void gemm128(const u16* __restrict__ Ah, const u16* __restrict__ Al,
             const u16* __restrict__ Bh, const u16* __restrict__ Bl,
             const float* __restrict__ bias, float* __restrict__ outF,
             u16* __restrict__ outB){
  constexpr int NBUF = (NSPLIT==3) ? 4 : 2;
  __shared__ u16 lds[NBUF * 4096];
  const int tid = threadIdx.x, w = tid >> 6, lane = tid & 63;
  const int wm = w & 1, wn = w >> 1;
  const int m0 = blockIdx.x * 128, n0 = blockIdx.y * 128;
  const int q = lane >> 4, rr = lane & 15;

  const int c0 = w*2, c1 = w*2 + 1;
  const int row0 = c0*16 + (lane >> 2), row1 = c1*16 + (lane >> 2);
  const int g0 = (lane & 3) ^ ((row0 >> 1) & 3);
  const int g1 = (lane & 3) ^ ((row1 >> 1) & 3);
  const size_t a0 = (size_t)(m0 + row0)*1024 + g0*8;
  const size_t a1 = (size_t)(m0 + row1)*1024 + g1*8;
  const size_t b0 = (size_t)(n0 + row0)*1024 + g0*8;
  const size_t b1 = (size_t)(n0 + row1)*1024 + g1*8;

  f32x4 acc[4][4];
  #pragma unroll
  for (int i=0;i<4;i++)
    #pragma unroll
    for (int j=0;j<4;j++) acc[i][j] = f32x4{0.f,0.f,0.f,0.f};

  for (int kt=0; kt<32; kt++){
    const int k0 = kt*32;
    gl_lds16(Ah + a0 + k0, lds + 0*4096 + c0*512);
    gl_lds16(Ah + a1 + k0, lds + 0*4096 + c1*512);
    gl_lds16(Bh + b0 + k0, lds + 1*4096 + c0*512);
    gl_lds16(Bh + b1 + k0, lds + 1*4096 + c1*512);
    if constexpr (NSPLIT == 3){
      gl_lds16(Al + a0 + k0, lds + 2*4096 + c0*512);
      gl_lds16(Al + a1 + k0, lds + 2*4096 + c1*512);
      gl_lds16(Bl + b0 + k0, lds + 3*4096 + c0*512);
      gl_lds16(Bl + b1 + k0, lds + 3*4096 + c1*512);
    }
    __syncthreads();   // drains vmcnt -> staged data visible

    short8 afh[4], bfh[4], afl[4], bfl[4];
    #pragma unroll
    for (int i=0;i<4;i++){
      int r  = wm*64 + i*16 + rr;
      int o  = r*32 + ((q ^ ((r >> 1) & 3))*8);
      afh[i] = *(const short8*)(lds + 0*4096 + o);
      if constexpr (NSPLIT == 3) afl[i] = *(const short8*)(lds + 2*4096 + o);
      int rn = wn*64 + i*16 + rr;
      int on = rn*32 + ((q ^ ((rn >> 1) & 3))*8);
      bfh[i] = *(const short8*)(lds + 1*4096 + on);
      if constexpr (NSPLIT == 3) bfl[i] = *(const short8*)(lds + 3*4096 + on);
    }
    #pragma unroll
    for (int i=0;i<4;i++)
      #pragma unroll
      for (int j=0;j<4;j++){
        acc[i][j] = mfma16(afh[i], bfh[j], acc[i][j]);
        if constexpr (NSPLIT == 3){
          acc[i][j] = mfma16(afh[i], bfl[j], acc[i][j]);
          acc[i][j] = mfma16(afl[i], bfh[j], acc[i][j]);
        }
      }
    __syncthreads();   // protect LDS from next kt's DMA
  }

  #pragma unroll
  for (int i=0;i<4;i++){
    #pragma unroll
    for (int j=0;j<4;j++){
      int n  = n0 + wn*64 + j*16 + rr;
      float bb = bias[n];
      if constexpr (EPI == 1){
        int mb = m0 + wm*64 + i*16 + q*4;
        us4 pk;
        #pragma unroll
        for (int r4=0;r4<4;r4++) pk[r4] = f2bf(acc[i][j][r4] + bb);
        *(us4*)(outB + ((size_t)((mb >> 12)*H_ + (n >> 6))*HD_ + (n & 63))*S_ + (mb & 4095)) = pk;
      } else {
        #pragma unroll
        for (int r4=0;r4<4;r4++){
          int m = m0 + wm*64 + i*16 + q*4 + r4;
          float v = acc[i][j][r4] + bb;
          if constexpr (EPI == 0)
            outF[((size_t)((m >> 12)*H_ + (n >> 6)))*S_*HD_ + (size_t)(m & 4095)*HD_ + (n & 63)] = v;
          else
            outF[(size_t)m*1024 + n] = v;
        }
      }
    }
  }
}

// ---------------- fused k-feature + kv' split-K partial ----------------
// grid (SPLITK_, BH_); block covers 512 s rows, 8 sub-chunks of 64.
// phase1: k' = exp(k@RF - ||k||^2/2) -> LDS [r][s] stride 72; phase2: kv += k'^T @ [v | 1]
__global__ __launch_bounds__(256, 1)
void kfeat_kv_kernel(const float* __restrict__ k32,
                     const u16* __restrict__ rfh, const u16* __restrict__ rfl,
                     const u16* __restrict__ vt, u16* __restrict__ kvp16){
  __shared__ u16 kp[R_*72];
  const int sp = blockIdx.x, hb = blockIdx.y, h = hb & 15;
  const int tid = threadIdx.x, w = tid >> 6, lane = tid & 63;
  const int q = lane >> 4, rr = lane & 15;

  short8 ones;
  { u16 one = (rr == 0) ? (u16)0x3F80 : (u16)0;
    #pragma unroll
    for (int j=0;j<8;j++) ones[j] = (short)one; }

  f32x4 acc2[4][5];
  #pragma unroll
  for (int a=0;a<4;a++)
    #pragma unroll
    for (int t=0;t<5;t++) acc2[a][t] = f32x4{0.f,0.f,0.f,0.f};

  for (int sub=0; sub<(S_/SPLITK_)/64; sub++){
    const int s0 = sp*(S_/SPLITK_) + sub*64;
    const float* ap = k32 + ((size_t)hb*S_ + s0 + w*16 + rr)*HD_ + q*8;
    float4 x0 = *(const float4*)(ap);
    float4 x1 = *(const float4*)(ap + 4);
    float4 x2 = *(const float4*)(ap + 32);
    float4 x3 = *(const float4*)(ap + 36);
    float sql[4];
    rowsq(x0, x1, x2, x3, q, sql);
    short8 ah[2], al[2];
    cvt8(x0, x1, ah[0], al[0]);
    cvt8(x2, x3, ah[1], al[1]);

    f32x4 accp[16];
    #pragma unroll
    for (int t=0;t<16;t++) accp[t] = f32x4{0.f,0.f,0.f,0.f};
    #pragma unroll
    for (int t=0;t<16;t++){
      const u16* bp  = rfh + ((size_t)h*R_ + t*16 + rr)*HD_ + q*8;
      const u16* bpl = rfl + ((size_t)h*R_ + t*16 + rr)*HD_ + q*8;
      short8 bh0 = *(const short8*)(bp);
      short8 bh1 = *(const short8*)(bp + 32);
      short8 bl0 = *(const short8*)(bpl);
      short8 bl1 = *(const short8*)(bpl + 32);
      f32x4 c = accp[t];
      c = mfma16(ah[0], bh0, c); c = mfma16(ah[0], bl0, c); c = mfma16(al[0], bh0, c);
      c = mfma16(ah[1], bh1, c); c = mfma16(ah[1], bl1, c); c = mfma16(al[1], bh1, c);
      accp[t] = c;
    }
    #pragma unroll
    for (int t=0;t<16;t++){
      us4 pk;
      #pragma unroll
      for (int r4=0;r4<4;r4++) pk[r4] = f2bf(__expf(accp[t][r4] - sql[r4]));
      *(us4*)(kp + (t*16 + rr)*72 + w*16 + q*4) = pk;
    }
    __syncthreads();
    #pragma unroll
    for (int ks=0; ks<2; ks++){
      short8 af[4];
      #pragma unroll
      for (int a=0;a<4;a++)
        af[a] = *(const short8*)(kp + (w*64 + a*16 + rr)*72 + ks*32 + q*8);
      #pragma unroll
      for (int t=0;t<5;t++){
        short8 bf;
        if (t < 4)
          bf = *(const short8*)(vt + ((size_t)hb*HD_ + t*16 + rr)*S_ + s0 + ks*32 + q*8);
        else
          bf = ones;
        #pragma unroll
        for (int a=0;a<4;a++) acc2[a][t] = mfma16(af[a], bf, acc2[a][t]);
      }
    }
    __syncthreads();
  }
  u16* op = kvp16 + ((size_t)hb*SPLITK_ + sp)*R_*80;
  #pragma unroll
  for (int a=0;a<4;a++)
    #pragma unroll
    for (int t=0;t<5;t++)
      #pragma unroll
      for (int r4=0;r4<4;r4++){
        int r = w*64 + a*16 + q*4 + r4;
        int c = t*16 + rr;
        op[r*80 + c] = f2bf(acc2[a][t][r4]);
      }
}

// reduce bf16 kv partials: kv_t[hb][d][r] bf16, ksum[hb][r] fp32
__global__ void kv_reduce_kernel(const u16* __restrict__ kvp16, u16* __restrict__ kvt,
                                 float* __restrict__ ksum){
  int r = blockIdx.x, hb = blockIdx.y, c = threadIdx.x;
  if (c >= 65) return;
  const u16* base = kvp16 + (size_t)hb*SPLITK_*R_*80 + r*80 + c;
  float s = 0.f;
  #pragma unroll
  for (int sp=0; sp<SPLITK_; sp++) s += bf2f(base[(size_t)sp*R_*80]);
  if (c < 64) kvt[((size_t)hb*HD_ + c)*R_ + r] = f2bf(s);
  else        ksum[(size_t)hb*R_ + r] = s;
}

// ---------------- fused q-feature + attn + norm ----------------
// grid (16, BH_); block covers 256 s rows, 4 sub-chunks of 64.
// norm = q'.ksum accumulated in-register from C-layout exp values; shfl_xor reduce over rr
// leaves norm for rows q*4+r4 exactly in the lanes that divide those rows in the epilogue.
__global__ __launch_bounds__(256, 1)
void qfeat_attn_kernel(const float* __restrict__ q32,
                       const u16* __restrict__ rfh, const u16* __restrict__ rfl,
                       const u16* __restrict__ kvt, const float* __restrict__ ksum,
                       u16* __restrict__ attn_c){
  __shared__ u16 qp[64*264];
  const int sc4 = blockIdx.x, hb = blockIdx.y, h = hb & 15, b = hb >> 4;
  const int tid = threadIdx.x, w = tid >> 6, lane = tid & 63;
  const int q = lane >> 4, rr = lane & 15;

  float kslv[16];
  #pragma unroll
  for (int t=0;t<16;t++) kslv[t] = ksum[(size_t)hb*R_ + t*16 + rr];

  for (int sub=0; sub<4; sub++){
    const int s0 = sc4*256 + sub*64;
    // ---- phase 1: q' for 64 s rows ----
    const float* ap = q32 + ((size_t)hb*S_ + s0 + w*16 + rr)*HD_ + q*8;
    float4 x0 = *(const float4*)(ap);
    float4 x1 = *(const float4*)(ap + 4);
    float4 x2 = *(const float4*)(ap + 32);
    float4 x3 = *(const float4*)(ap + 36);
    float sql[4];
    rowsq(x0, x1, x2, x3, q, sql);
    short8 ah[2], al[2];
    cvt8(x0, x1, ah[0], al[0]);
    cvt8(x2, x3, ah[1], al[1]);

    f32x4 accp[16];
    #pragma unroll
    for (int t=0;t<16;t++) accp[t] = f32x4{0.f,0.f,0.f,0.f};
    #pragma unroll
    for (int t=0;t<16;t++){
      const u16* bp  = rfh + ((size_t)h*R_ + t*16 + rr)*HD_ + q*8;
      const u16* bpl = rfl + ((size_t)h*R_ + t*16 + rr)*HD_ + q*8;
      short8 bh0 = *(const short8*)(bp);
      short8 bh1 = *(const short8*)(bp + 32);
      short8 bl0 = *(const short8*)(bpl);
      short8 bl1 = *(const short8*)(bpl + 32);
      f32x4 c = accp[t];
      c = mfma16(ah[0], bh0, c); c = mfma16(ah[0], bl0, c); c = mfma16(al[0], bh0, c);
      c = mfma16(ah[1], bh1, c); c = mfma16(ah[1], bl1, c); c = mfma16(al[1], bh1, c);
      accp[t] = c;
    }
    // exp -> qp (A-layout staging) + in-register norm partials
    float npl[4] = {0.f, 0.f, 0.f, 0.f};
    #pragma unroll
    for (int t=0;t<16;t++){
      us4 pk;
      #pragma unroll
      for (int r4=0;r4<4;r4++){
        float e = __expf(accp[t][r4] - sql[r4]);
        npl[r4] += e * kslv[t];
        pk[r4] = f2bf(e);
      }
      #pragma unroll
      for (int r4=0;r4<4;r4++)
        qp[(w*16 + q*4 + r4)*264 + t*16 + rr] = pk[r4];
    }
    // reduce norm over rr (bits 0-3 of lane) -> lanes keep rows q*4+r4
    #pragma unroll
    for (int r4=0;r4<4;r4++){
      npl[r4] += __shfl_xor(npl[r4], 1);
      npl[r4] += __shfl_xor(npl[r4], 2);
      npl[r4] += __shfl_xor(npl[r4], 4);
      npl[r4] += __shfl_xor(npl[r4], 8);
    }
    __syncthreads();

    // ---- phase 2: attn = q' @ kv'^T ; wave w owns s rows w*16..w*16+15 ----
    f32x4 acc[4];
    #pragma unroll
    for (int t=0;t<4;t++) acc[t] = f32x4{0.f,0.f,0.f,0.f};
    #pragma unroll
    for (int ks=0; ks<8; ks++){
      short8 af = *(const short8*)(qp + (w*16 + rr)*264 + ks*32 + q*8);
      #pragma unroll
      for (int t=0;t<4;t++){
        short8 bf = *(const short8*)(kvt + ((size_t)hb*HD_ + t*16 + rr)*R_ + ks*32 + q*8);
        acc[t] = mfma16(af, bf, acc[t]);
      }
    }

    #pragma unroll
    for (int t=0;t<4;t++)
      #pragma unroll
      for (int r4=0;r4<4;r4++){
        int sl = w*16 + q*4 + r4;
        int d  = t*16 + rr;
        float o = acc[t][r4] / (npl[r4] + 1e-6f);
        attn_c[((size_t)b*S_ + s0 + sl)*D_ + h*HD_ + d] = f2bf(o);
      }
    __syncthreads();   // qp reuse next sub-chunk
  }
}

// ---------------- host ----------------
extern "C" void kernel_launch(void* const* d_in, const int* in_sizes, int n_in,
                              void* d_out, int out_size, void* d_ws, size_t ws_size,
                              hipStream_t stream){
  (void)in_sizes; (void)n_in; (void)out_size; (void)ws_size;
  const float* x  = (const float*)d_in[0];
  const float* wq = (const float*)d_in[1];
  const float* bq = (const float*)d_in[2];
  const float* wk = (const float*)d_in[3];
  const float* bk = (const float*)d_in[4];
  const float* wv = (const float*)d_in[5];
  const float* bv = (const float*)d_in[6];
  const float* wo = (const float*)d_in[7];
  const float* bo = (const float*)d_in[8];
  const float* rf = (const float*)d_in[9];
  float* out = (float*)d_out;

  char* p = (char*)d_ws;
  size_t off = 0;
  auto take = [&](size_t bytes)->char*{
    char* r = p + off; off += (bytes + 255) & ~(size_t)255; return r;
  };
  u16*  x_hi  = (u16*)take((size_t)M_*D_*2);
  u16*  x_lo  = (u16*)take((size_t)M_*D_*2);
  u16*  wq_hi = (u16*)take((size_t)D_*D_*2);
  u16*  wq_lo = (u16*)take((size_t)D_*D_*2);
  u16*  wk_hi = (u16*)take((size_t)D_*D_*2);
  u16*  wk_lo = (u16*)take((size_t)D_*D_*2);
  u16*  wv_hi = (u16*)take((size_t)D_*D_*2);
  u16*  wo_hi = (u16*)take((size_t)D_*D_*2);
  u16*  rf_hi = (u16*)take((size_t)H_*R_*HD_*2);
  u16*  rf_lo = (u16*)take((size_t)H_*R_*HD_*2);
  float* q32  = (float*)take((size_t)M_*D_*4);
  float* k32  = (float*)take((size_t)M_*D_*4);
  u16*  v_t   = (u16*)take((size_t)M_*D_*2);
  u16*  kvt   = (u16*)take((size_t)BH_*HD_*R_*2);
  float* ksum = (float*)take((size_t)BH_*R_*4);
  // aliases (stream-ordered reuse of dead buffers):
  u16* attn_c = x_hi;   // x_hi dead after V projection
  u16* kvp16  = x_lo;   // x_lo dead after K projection; 21 MB <= 33.5 MB

  // prep: splits
  split_kernel<<<dim3((M_*D_)/1024), 256, 0, stream>>>(x,  x_hi,  x_lo,  (M_*D_)/4);
  split_kernel<<<dim3((D_*D_)/1024), 256, 0, stream>>>(wq, wq_hi, wq_lo, (D_*D_)/4);
  split_kernel<<<dim3((D_*D_)/1024), 256, 0, stream>>>(wk, wk_hi, wk_lo, (D_*D_)/4);
  split_kernel<<<dim3((D_*D_)/1024), 256, 0, stream>>>(wv, wv_hi, nullptr, (D_*D_)/4);
  split_kernel<<<dim3((D_*D_)/1024), 256, 0, stream>>>(wo, wo_hi, nullptr, (D_*D_)/4);
  rf_split_kernel<<<dim3((H_*R_*HD_)/256), 256, 0, stream>>>(rf, rf_hi, rf_lo);

  // projections
  gemm128<3,0><<<dim3(M_/128, D_/128), 256, 0, stream>>>(x_hi, x_lo, wq_hi, wq_lo, bq, q32, nullptr);
  gemm128<3,0><<<dim3(M_/128, D_/128), 256, 0, stream>>>(x_hi, x_lo, wk_hi, wk_lo, bk, k32, nullptr);
  gemm128<1,1><<<dim3(M_/128, D_/128), 256, 0, stream>>>(x_hi, nullptr, wv_hi, nullptr, bv, nullptr, v_t);

  // k' -> kv partials -> reduce
  kfeat_kv_kernel<<<dim3(SPLITK_, BH_), 256, 0, stream>>>(k32, rf_hi, rf_lo, v_t, kvp16);
  kv_reduce_kernel<<<dim3(R_, BH_), 128, 0, stream>>>(kvp16, kvt, ksum);

  // q' -> attn -> attn_c
  qfeat_attn_kernel<<<dim3(16, BH_), 256, 0, stream>>>(q32, rf_hi, rf_lo, kvt, ksum, attn_c);

  // output projection
  gemm128<1,2><<<dim3(M_/128, D_/128), 256, 0, stream>>>(attn_c, nullptr, wo_hi, nullptr, bo, out, nullptr);
}